// Round 7
// baseline (688.032 us; speedup 1.0000x reference)
//
#include <hip/hip_runtime.h>
#include <stdint.h>

// IndexNSW: batched greedy best-first NSW search. One WAVE per query
// (B=64 blocks x 64 threads), zero barriers (single-wave lockstep; DS ops
// are program-ordered within a wave).
//
// R7 vs R6 (544us): R6's register-resident coalesced gather was serialized
// by the allocator (VGPR=120 < the 128 needed for r[32] => load->wait->FMA
// per row = 32 serial HBM trips/step). Fix: stage rows via
// __builtin_amdgcn_global_load_lds width=16 -- per-lane gaddr rowbase+16l
// (coalesced 1KB/instr), LDS dest uniform base + 16*lane, ZERO VGPRs held.
// All 32 stages issue back-to-back (vmcnt), visited-bitmap work overlaps
// the drain, one s_waitcnt vmcnt(0), then 32 conflict-free ds_read_b128
// (lane l -> float4 l of row j) feed the R6-verified transpose-reduce
// butterfly (keep w[2i+lb], shuffle w[2i+(1-lb)]).
// Merge key = (f32 bits of d)<<6 | concat idx: d>=0 so u64 order ==
// (d, idx) lexicographic == lax.top_k stable order (ties incl. dup ids).

#define DIMS   256
#define RDEG   32
#define EFPOOL 32
#define KOUT   10
#define NWORDS 3125     // ceil(100000 / 32)
#define INF_D  1e30f

typedef __attribute__((address_space(3))) uint32_t       lds_u32_t;
typedef const __attribute__((address_space(1))) uint32_t glb_u32_t;

__global__ __launch_bounds__(64, 1) void nsw_wave_kernel(
    const float* __restrict__ query,    // [B, 256]
    const float* __restrict__ storage,  // [N, 256]
    const int*   __restrict__ graph,    // [N, 32]
    const int*   __restrict__ initial,  // [B, 32]
    float*       __restrict__ out,      // [B*10 ids as float][B*10 dists]
    int B)
{
    __shared__ unsigned int visited[NWORDS];
    __shared__ unsigned int expanded[NWORDS];
    __shared__ float rows[RDEG * DIMS];         // 32 KB staged candidate rows
    __shared__ unsigned long long keys[64];     // merge keys
    __shared__ float sc_d[EFPOOL];              // merge scatter scratch
    __shared__ int   sc_id[EFPOOL];

    const int l    = threadIdx.x;   // 0..63
    const int b    = blockIdx.x;
    const int nb   = l & 31;        // pool slot / row owned (dup across halves)
    const int half = l >> 5;

    for (int i = l; i < NWORDS; i += 64) { visited[i] = 0u; expanded[i] = 0u; }

    // lane's 4 query dims [4l, 4l+4) in registers
    const float4 q = reinterpret_cast<const float4*>(query + (size_t)b * DIMS)[l];

    float pool_d  = INF_D;   // dummy pool; first merge sorts the real entries in
    int   pool_id = 0;
    int   u = 0;             // next node to expand (set by merge_pick)

    // Stage 32 rows into LDS: instruction j moves row id_j (1KB) whole-wave.
    // Per-lane gaddr = rowbase + 16*l; LDS dest = rows + 1024*j + 16*lane.
    // No destination VGPRs -> all 32 stay in flight until the single drain.
    auto stage32 = [&](int nbid) {
        #pragma unroll
        for (int j = 0; j < 32; ++j) {
            int idj = __shfl(nbid, j, 64);      // row id, broadcast from lane j
            const float* gp = storage + (size_t)idj * DIMS + 4 * l;
            __builtin_amdgcn_global_load_lds((glb_u32_t*)gp,
                                             (lds_u32_t*)&rows[j * DIMS],
                                             16, 0, 0);
        }
    };

    // After the drain: distances of the 32 staged rows; D(row l&31) in every
    // lane. Readback is conflict-free (lane l -> float4 l: sequential banks).
    auto dist32 = [&]() -> float {
        float w[32];
        #pragma unroll
        for (int j = 0; j < 32; ++j) {
            float4 r = reinterpret_cast<const float4*>(rows)[j * (DIMS / 4) + l];
            float d0 = r.x - q.x; float a = d0 * d0;
            float d1 = r.y - q.y; a = fmaf(d1, d1, a);
            float d2 = r.z - q.z; a = fmaf(d2, d2, a);
            float d3 = r.w - q.w; a = fmaf(d3, d3, a);
            w[j] = a;
        }
        // transpose-reduce (R6-verified): keep w[2i+lb], shuffle w[2i+(1-lb)]
        // (partner sends the row we kept). After stage k, w[i](l) = partial
        // of row i*2^(k+1) + (l mod 2^(k+1)) over lanes agreeing on bits k+1..5.
        #pragma unroll
        for (int k = 0; k < 5; ++k) {
            const int m  = 1 << k;
            const int lb = (l >> k) & 1;
            #pragma unroll
            for (int i = 0; i < (16 >> k); ++i) {
                float mine  = w[2 * i + lb];
                float other = w[2 * i + (1 - lb)];
                w[i] = mine + __shfl_xor(other, m, 64);
            }
        }
        return w[0] + __shfl_xor(w[0], 32, 64); // D(row l&31), all lanes
    };

    // merge 64 concat elements (lane l owns concat idx l: [0,32)=old pool,
    // [32,64)=new cands) == lax.top_k(-all_d, 32); then pick next u = first
    // unexpanded slot of the sorted pool (== reference argmin).
    auto merge_pick = [&](float nd, int nbid) {
        float ed  = half ? nd   : pool_d;
        int   eid = half ? nbid : pool_id;
        unsigned long long key =
            ((unsigned long long)__float_as_uint(ed) << 6) | (unsigned)l;
        keys[l] = key;
        int rank = 0;
        #pragma unroll
        for (int j = 0; j < 64; ++j)            // same addr all lanes: broadcast
            rank += (keys[j] < key) ? 1 : 0;
        if (rank < EFPOOL) { sc_d[rank] = ed; sc_id[rank] = eid; }  // ranks unique
        pool_d  = sc_d[nb];                     // in-order DS: no barrier
        pool_id = sc_id[nb];
        bool unexp = !((expanded[pool_id >> 5] >> (pool_id & 31)) & 1u);
        unsigned long long m = __ballot(unexp && (l < 32));
        int slot = (m == 0ull) ? 0 : (__ffsll(m) - 1);
        u = __builtin_amdgcn_readfirstlane(sc_id[slot]);
        if (l == 0) expanded[u >> 5] |= (1u << (u & 31));   // sole writer
    };

    // ---- initial pool: dists of init ids, merged vs dummy INF pool ----
    {
        int nbid = initial[b * EFPOOL + nb];    // halves duplicate
        stage32(nbid);
        if (l < 32) atomicOr(&visited[nbid >> 5], 1u << (nbid & 31));
        __builtin_amdgcn_s_waitcnt(0x0f70);     // vmcnt(0) only
        float nd = dist32();
        merge_pick(nd, nbid);
    }

    // ---- ef_search expansion steps ----
    for (int step = 0; step < EFPOOL; ++step) {
        // neighbor ids: coalesced 128B row (halves duplicate)
        int nbid = graph[(size_t)u * RDEG + nb];

        stage32(nbid);                          // 32 row-stages in flight

        // fresh = !visited pre-update, overlapped with the global drain
        // (reads precede ORs: program order within the wave)
        unsigned vw = visited[nbid >> 5];
        bool fresh = !((vw >> (nbid & 31)) & 1u);
        if ((l < 32) && fresh) atomicOr(&visited[nbid >> 5], 1u << (nbid & 31));

        __builtin_amdgcn_s_waitcnt(0x0f70);     // vmcnt(0) only
        float d = dist32();
        float nd = fresh ? d : INF_D;
        merge_pick(nd, nbid);
    }

    // ---- output: pool sorted ascending; ids as float (exact < 2^24), then dists ----
    if (l < KOUT) {
        out[b * KOUT + l]            = (float)pool_id;
        out[B * KOUT + b * KOUT + l] = pool_d;
    }
}

extern "C" void kernel_launch(void* const* d_in, const int* in_sizes, int n_in,
                              void* d_out, int out_size, void* d_ws, size_t ws_size,
                              hipStream_t stream) {
    const float* query   = (const float*)d_in[0];
    const float* storage = (const float*)d_in[1];
    const int*   graph   = (const int*)d_in[2];
    const int*   initial = (const int*)d_in[3];
    float* out = (float*)d_out;

    const int B = in_sizes[0] / DIMS;   // 64

    nsw_wave_kernel<<<B, 64, 0, stream>>>(query, storage, graph, initial, out, B);
}

// Round 8
// 240.131 us; speedup vs baseline: 2.8652x; 2.8652x over previous
//
#include <hip/hip_runtime.h>

// IndexNSW: batched greedy best-first NSW search. One workgroup per query:
// 256 threads = 4 waves. tid t -> (row = t>>3, chunk c = t&7): each of the
// 32 candidate rows is covered by 8 lanes x 32 dims = 8 float4 loads/lane.
//
// R8 rationale (R6/R7 post-mortem): wave-wide "row j per instruction"
// gathers (register or global_load_lds) got issue-chained by the compiler ->
// 32 serial HBM trips/step (544/559us). R4's per-lane divergent gather ran
// 103us but its r[32] batch (128 VGPRs) was partially rolled (2-3 trips).
// Here the per-lane batch is r[8] (32 VGPRs, ~94 VGPR total demand) -> all
// loads in flight, ONE memory latency per step.
//
// Merge/pick is the R4-verified machinery, run on wave 0 only (its 64 lanes
// = 64 concat elements). Visited-bitmap read-before-write (duplicate-id
// semantics) stays wave-0-internal: wave 0 re-reads the 32-id graph row,
// computes fresh flags + ORs in program order, passes mask via __ballot.
// 2 barriers/step. Merge key = (f32 bits of d)<<6 | concat idx: d>=0 so
// u64 order == (d, idx) lexicographic == lax.top_k stable order.

#define DIMS   256
#define RDEG   32
#define EFPOOL 32
#define KOUT   10
#define NWORDS 3125     // ceil(100000 / 32)
#define INF_D  1e30f

__global__ __launch_bounds__(256, 1) void nsw_kernel(
    const float* __restrict__ query,    // [B, 256]
    const float* __restrict__ storage,  // [N, 256]
    const int*   __restrict__ graph,    // [N, 32]
    const int*   __restrict__ initial,  // [B, 32]
    float*       __restrict__ out,      // [B*10 ids as float][B*10 dists]
    int B)
{
    __shared__ unsigned int visited[NWORDS];
    __shared__ unsigned int expanded[NWORDS];
    __shared__ float sc_d[EFPOOL];              // pool (always top_k-sorted)
    __shared__ int   sc_id[EFPOOL];
    __shared__ float cand_d[RDEG];              // this step's raw distances
    __shared__ int   cand_id[RDEG];
    __shared__ unsigned long long keys[64];     // merge keys
    __shared__ int s_u;

    const int t   = threadIdx.x;    // 0..255
    const int b   = blockIdx.x;
    const int row = t >> 3;         // candidate row 0..31
    const int c   = t & 7;          // 32-dim chunk within the row
    const int l   = t & 63;         // lane within wave
    const int w   = t >> 6;         // wave 0..3

    for (int i = t; i < NWORDS; i += 256) { visited[i] = 0u; expanded[i] = 0u; }
    if (t < EFPOOL) { sc_d[t] = INF_D; sc_id[t] = 0; }  // dummy pool, sorted in by 1st merge

    // lane's 32 query dims [c*32, c*32+32) in registers
    float4 q[8];
    {
        const float4* qp = reinterpret_cast<const float4*>(query + (size_t)b * DIMS) + c * 8;
        #pragma unroll
        for (int j = 0; j < 8; ++j) q[j] = qp[j];
    }
    __syncthreads();    // bitmaps zeroed, dummy pool visible

    // this lane's 32-dim partial of row id, then 3-stage reduce over the
    // row's 8 lanes (c = bits 0..2 of t, all within one wave)
    auto rowdist = [&](int id) -> float {
        const float4* sp = reinterpret_cast<const float4*>(storage + (size_t)id * DIMS) + c * 8;
        float4 r[8];
        #pragma unroll
        for (int j = 0; j < 8; ++j) r[j] = sp[j];       // 8 loads in flight
        float a0 = 0.f, a1 = 0.f, a2 = 0.f, a3 = 0.f;
        #pragma unroll
        for (int j = 0; j < 8; ++j) {
            float d0 = r[j].x - q[j].x; a0 = fmaf(d0, d0, a0);
            float d1 = r[j].y - q[j].y; a1 = fmaf(d1, d1, a1);
            float d2 = r[j].z - q[j].z; a2 = fmaf(d2, d2, a2);
            float d3 = r[j].w - q[j].w; a3 = fmaf(d3, d3, a3);
        }
        float a = (a0 + a1) + (a2 + a3);
        a += __shfl_xor(a, 1, 64);
        a += __shfl_xor(a, 2, 64);
        a += __shfl_xor(a, 4, 64);
        return a;       // full distance of row, in all 8 of its lanes
    };

    // wave-0-only: merge 64 concat elems (lane l: [0,32)=old pool from sc_*,
    // [32,64)=cand l-32 masked by fmask) == lax.top_k(-all_d, 32); write new
    // sorted pool back to sc_*; pick u = first unexpanded slot (== reference
    // argmin on the sorted pool); mark expanded; publish s_u.
    auto merge_pick = [&](unsigned fmask) {
        float ed; int eid;
        if (l < 32) { ed = sc_d[l]; eid = sc_id[l]; }
        else {
            bool fr = (fmask >> (l - 32)) & 1u;
            ed  = fr ? cand_d[l - 32] : INF_D;
            eid = cand_id[l - 32];
        }
        unsigned long long key =
            ((unsigned long long)__float_as_uint(ed) << 6) | (unsigned)l;
        keys[l] = key;
        int rank = 0;
        #pragma unroll
        for (int j = 0; j < 64; ++j)            // same addr all lanes: broadcast
            rank += (keys[j] < key) ? 1 : 0;
        // old-pool reads all happened above; in-wave program order => safe
        if (rank < EFPOOL) { sc_d[rank] = ed; sc_id[rank] = eid; }  // ranks unique
        int pid = sc_id[l & 31];
        bool unexp = !((expanded[pid >> 5] >> (pid & 31)) & 1u);
        unsigned long long m = __ballot(unexp && (l < 32));
        int slot = (m == 0ull) ? 0 : (__ffsll(m) - 1);
        int u = __builtin_amdgcn_readfirstlane(sc_id[slot]);
        if (l == 0) {
            expanded[u >> 5] |= (1u << (u & 31));   // sole writer
            s_u = u;
        }
    };

    // ---- initial pool: mark visited, distances, merge vs dummy INF pool ----
    {
        if (w == 0 && l < 32) {
            int id = initial[b * EFPOOL + l];
            atomicOr(&visited[id >> 5], 1u << (id & 31));
        }
        int nbid = initial[b * EFPOOL + row];
        float d = rowdist(nbid);
        if (c == 0) { cand_d[row] = d; cand_id[row] = nbid; }
        __syncthreads();
        if (w == 0) merge_pick(0xffffffffu);    // all init entries live
        __syncthreads();
    }

    // ---- ef_search expansion steps ----
    for (int step = 0; step < EFPOOL; ++step) {
        int u = __builtin_amdgcn_readfirstlane(s_u);

        // all waves: this row's neighbor id + unconditional storage gather
        int nbid = graph[(size_t)u * RDEG + row];
        float d = rowdist(nbid);

        // wave 0: fresh flags for all 32 neighbors, read-all-then-OR in
        // program order (duplicate ids in one row each count as fresh, as in
        // the reference's pre-update visited read)
        unsigned fmask = 0u;
        if (w == 0) {
            bool fresh = false;
            if (l < 32) {
                int nl = graph[(size_t)u * RDEG + l];
                fresh = !((visited[nl >> 5] >> (nl & 31)) & 1u);
                if (fresh) atomicOr(&visited[nl >> 5], 1u << (nl & 31));
            }
            fmask = (unsigned)__ballot(fresh);  // bits 0..31
        }

        if (c == 0) { cand_d[row] = d; cand_id[row] = nbid; }
        __syncthreads();
        if (w == 0) merge_pick(fmask);
        __syncthreads();
    }

    // ---- output: pool sorted ascending; ids as float (exact < 2^24), then dists ----
    if (t < KOUT) {
        out[b * KOUT + t]                      = (float)sc_id[t];
        out[(size_t)B * KOUT + b * KOUT + t]   = sc_d[t];
    }
}

extern "C" void kernel_launch(void* const* d_in, const int* in_sizes, int n_in,
                              void* d_out, int out_size, void* d_ws, size_t ws_size,
                              hipStream_t stream) {
    const float* query   = (const float*)d_in[0];
    const float* storage = (const float*)d_in[1];
    const int*   graph   = (const int*)d_in[2];
    const int*   initial = (const int*)d_in[3];
    float* out = (float*)d_out;

    const int B = in_sizes[0] / DIMS;   // 64

    nsw_kernel<<<B, 256, 0, stream>>>(query, storage, graph, initial, out, B);
}

// Round 9
// 235.327 us; speedup vs baseline: 2.9237x; 1.0204x over previous
//
#include <hip/hip_runtime.h>
#include <stdint.h>

// IndexNSW: batched greedy best-first NSW search. One workgroup per query:
// 256 threads = 4 waves. tid t -> (row = t>>3, chunk c = t&7): each of the
// 32 candidate rows is covered by 8 lanes x 32 dims = 8 float4 loads/lane.
//
// R9 vs R8 (109us dispatch, VGPR=44):
//  1) sched_barrier(0) between the 8-load batch and the FMAs in rowdist.
//     R8's scheduler interleaved load j with use j-1 (VGPR=44 proves only
//     ~2-3 loads in flight) => 2-3 serial memory trips/step. The barrier
//     forces all 8 loads issued before any use -> one trip. (R3/R6/R7/R8
//     all showed the compiler never keeps a gather in flight voluntarily.)
//  2) graph-row prefetch: u(s+1) is always one of the 64 pre-merge concat
//     candidates. While wave 0 merges, waves 1-2 touch offsets 0/64B of all
//     64 candidates' 128B graph rows via global_load_lds width=4 into dead
//     LDS scratch (pure L2-warmer, never waited on, data never read) ->
//     next step's graph read is L2-hit instead of L3.
//
// Merge/pick (R4/R8-verified): wave 0's 64 lanes = 64 concat elements; key
// = (f32 bits of d)<<6 | concat idx; d>=0 so u64 order == (d, idx)
// lexicographic == lax.top_k stable order. Visited-bitmap read-before-OR
// (duplicate-id semantics) is wave-0-internal, program-ordered.

#define DIMS   256
#define RDEG   32
#define EFPOOL 32
#define KOUT   10
#define NWORDS 3125     // ceil(100000 / 32)
#define INF_D  1e30f

typedef __attribute__((address_space(3))) uint32_t       lds_u32_t;
typedef const __attribute__((address_space(1))) uint32_t glb_u32_t;

__global__ __launch_bounds__(256, 1) void nsw_kernel(
    const float* __restrict__ query,    // [B, 256]
    const float* __restrict__ storage,  // [N, 256]
    const int*   __restrict__ graph,    // [N, 32]
    const int*   __restrict__ initial,  // [B, 32]
    float*       __restrict__ out,      // [B*10 ids as float][B*10 dists]
    int B)
{
    __shared__ unsigned int visited[NWORDS];
    __shared__ unsigned int expanded[NWORDS];
    __shared__ float sc_d[EFPOOL];              // pool (always top_k-sorted)
    __shared__ int   sc_id[EFPOOL];
    __shared__ float cand_d[RDEG];              // this step's raw distances
    __shared__ int   cand_id[RDEG];
    __shared__ int   pref_id[2 * EFPOOL];       // 64 prefetch candidate ids
    __shared__ int   pref_scratch[128];         // dead dest for prefetch loads
    __shared__ unsigned long long keys[64];     // merge keys
    __shared__ int s_u;

    const int t   = threadIdx.x;    // 0..255
    const int b   = blockIdx.x;
    const int row = t >> 3;         // candidate row 0..31
    const int c   = t & 7;          // 32-dim chunk within the row
    const int l   = t & 63;         // lane within wave
    const int w   = t >> 6;         // wave 0..3

    for (int i = t; i < NWORDS; i += 256) { visited[i] = 0u; expanded[i] = 0u; }
    if (t < EFPOOL) { sc_d[t] = INF_D; sc_id[t] = 0; }  // dummy pool, sorted in by 1st merge

    // lane's 32 query dims [c*32, c*32+32) in registers
    float4 q[8];
    {
        const float4* qp = reinterpret_cast<const float4*>(query + (size_t)b * DIMS) + c * 8;
        #pragma unroll
        for (int j = 0; j < 8; ++j) q[j] = qp[j];
    }
    __syncthreads();    // bitmaps zeroed, dummy pool visible

    // this lane's 32-dim partial of row id, then 3-stage reduce over the
    // row's 8 lanes (c = bits 0..2 of t, all within one wave)
    auto rowdist = [&](int id) -> float {
        const float4* sp = reinterpret_cast<const float4*>(storage + (size_t)id * DIMS) + c * 8;
        float4 r[8];
        #pragma unroll
        for (int j = 0; j < 8; ++j) r[j] = sp[j];       // 8 loads...
        __builtin_amdgcn_sched_barrier(0);              // ...ALL issued before any use
        float a0 = 0.f, a1 = 0.f, a2 = 0.f, a3 = 0.f;
        #pragma unroll
        for (int j = 0; j < 8; ++j) {
            float d0 = r[j].x - q[j].x; a0 = fmaf(d0, d0, a0);
            float d1 = r[j].y - q[j].y; a1 = fmaf(d1, d1, a1);
            float d2 = r[j].z - q[j].z; a2 = fmaf(d2, d2, a2);
            float d3 = r[j].w - q[j].w; a3 = fmaf(d3, d3, a3);
        }
        float a = (a0 + a1) + (a2 + a3);
        a += __shfl_xor(a, 1, 64);
        a += __shfl_xor(a, 2, 64);
        a += __shfl_xor(a, 4, 64);
        return a;       // full distance of row, in all 8 of its lanes
    };

    // wave-0-only: merge 64 concat elems (lane l: [0,32)=old pool from sc_*,
    // [32,64)=cand l-32 masked by fmask) == lax.top_k(-all_d, 32); write new
    // sorted pool back to sc_*; pick u = first unexpanded slot (== reference
    // argmin on the sorted pool); mark expanded; publish s_u.
    auto merge_pick = [&](unsigned fmask) {
        float ed; int eid;
        if (l < 32) { ed = sc_d[l]; eid = sc_id[l]; }
        else {
            bool fr = (fmask >> (l - 32)) & 1u;
            ed  = fr ? cand_d[l - 32] : INF_D;
            eid = cand_id[l - 32];
        }
        unsigned long long key =
            ((unsigned long long)__float_as_uint(ed) << 6) | (unsigned)l;
        keys[l] = key;
        int rank = 0;
        #pragma unroll
        for (int j = 0; j < 64; ++j)            // same addr all lanes: broadcast
            rank += (keys[j] < key) ? 1 : 0;
        // old-pool reads all happened above; in-wave program order => safe
        if (rank < EFPOOL) { sc_d[rank] = ed; sc_id[rank] = eid; }  // ranks unique
        int pid = sc_id[l & 31];
        bool unexp = !((expanded[pid >> 5] >> (pid & 31)) & 1u);
        unsigned long long m = __ballot(unexp && (l < 32));
        int slot = (m == 0ull) ? 0 : (__ffsll(m) - 1);
        int u = __builtin_amdgcn_readfirstlane(sc_id[slot]);
        if (l == 0) {
            expanded[u >> 5] |= (1u << (u & 31));   // sole writer
            s_u = u;
        }
    };

    // ---- initial pool: mark visited, distances, merge vs dummy INF pool ----
    {
        if (w == 0 && l < 32) {
            int id = initial[b * EFPOOL + l];
            atomicOr(&visited[id >> 5], 1u << (id & 31));
        }
        int nbid = initial[b * EFPOOL + row];
        float d = rowdist(nbid);
        if (c == 0) { cand_d[row] = d; cand_id[row] = nbid; pref_id[32 + row] = nbid; }
        if (t < 32) pref_id[t] = sc_id[t];
        __syncthreads();
        if (w == 0) merge_pick(0xffffffffu);    // all init entries live
        if (w == 1 || w == 2) {                 // warm L2 with candidate graph rows
            int pid = pref_id[l];
            const int* gp = graph + (size_t)pid * RDEG + (w == 2 ? 16 : 0); // 0 / +64B
            __builtin_amdgcn_global_load_lds((glb_u32_t*)gp,
                                             (lds_u32_t*)&pref_scratch[(w - 1) * 64],
                                             4, 0, 0);
        }
        __syncthreads();
    }

    // ---- ef_search expansion steps ----
    for (int step = 0; step < EFPOOL; ++step) {
        int u = __builtin_amdgcn_readfirstlane(s_u);

        // all waves: this row's neighbor id + unconditional storage gather
        int nbid = graph[(size_t)u * RDEG + row];
        float d = rowdist(nbid);

        // wave 0: fresh flags for all 32 neighbors, read-all-then-OR in
        // program order (duplicate ids in one row each count as fresh, as in
        // the reference's pre-update visited read)
        unsigned fmask = 0u;
        if (w == 0) {
            bool fresh = false;
            if (l < 32) {
                int nl = graph[(size_t)u * RDEG + l];
                fresh = !((visited[nl >> 5] >> (nl & 31)) & 1u);
                if (fresh) atomicOr(&visited[nl >> 5], 1u << (nl & 31));
            }
            fmask = (unsigned)__ballot(fresh);  // bits 0..31
        }

        if (c == 0) { cand_d[row] = d; cand_id[row] = nbid; pref_id[32 + row] = nbid; }
        if (t < 32) pref_id[t] = sc_id[t];      // pre-merge pool ids
        __syncthreads();
        if (w == 0) merge_pick(fmask);
        if (w == 1 || w == 2) {                 // hidden under the merge:
            int pid = pref_id[l];               // u(s+1) is one of these 64
            const int* gp = graph + (size_t)pid * RDEG + (w == 2 ? 16 : 0);
            __builtin_amdgcn_global_load_lds((glb_u32_t*)gp,
                                             (lds_u32_t*)&pref_scratch[(w - 1) * 64],
                                             4, 0, 0);
        }
        __syncthreads();
    }

    // ---- output: pool sorted ascending; ids as float (exact < 2^24), then dists ----
    if (t < KOUT) {
        out[b * KOUT + t]                      = (float)sc_id[t];
        out[(size_t)B * KOUT + b * KOUT + t]   = sc_d[t];
    }
}

extern "C" void kernel_launch(void* const* d_in, const int* in_sizes, int n_in,
                              void* d_out, int out_size, void* d_ws, size_t ws_size,
                              hipStream_t stream) {
    const float* query   = (const float*)d_in[0];
    const float* storage = (const float*)d_in[1];
    const int*   graph   = (const int*)d_in[2];
    const int*   initial = (const int*)d_in[3];
    float* out = (float*)d_out;

    const int B = in_sizes[0] / DIMS;   // 64

    nsw_kernel<<<B, 256, 0, stream>>>(query, storage, graph, initial, out, B);
}